// Round 1
// 444.991 us; speedup vs baseline: 1.0336x; 1.0336x over previous
//
#include <hip/hip_runtime.h>

// Mamba selective scan, fp32. u,delta,z:(4,2048,2048) A:(2048,16)
// B,C:(4,16,2048) D:(2048,). Output y:(4,2048,2048).
// 3-pass chunked scan (chunk op = (S=sum dt, q=local scan)).
// R4: kill the 64-way address divergence. Previously each wave64 float4
// load/store had lane stride 8KB -> 64 cache-line lookups per instruction
// (TA/TCP request-rate bound; WRITE_SIZE showed 2.85x amplification).
// Now all global I/O is cooperative + lane-along-t (16 full lines per
// instruction, the minimum), transposed through padded LDS (stride 20
// floats -> conflict-free b128 in every phase). B/C transposed once per
// chunk into LDS [t][n] so the inner loop reads them as uniform float4
// broadcasts. Pass2 parallelized over (n, bd).

#define BATCHSZ 4
#define DIN 2048
#define NSTATE 16
#define SEQ 2048
#define NCH (BATCHSZ * DIN)     // 8192 channels
#define NGRP (NCH / 256)        // 32 channel-groups of 256
#define TT 16                   // time tile per LDS stage
#define ST 20                   // padded LDS row stride in floats (16B-aligned,
                                // slot=(5*row+col)&7 -> conflict-free b128)
#define L2E 1.44269504f

__device__ __forceinline__ float softplus_f(float v) {
    float e = __builtin_amdgcn_exp2f(v * L2E);
    return 0.69314718f * __builtin_amdgcn_logf(1.0f + e);
}

__device__ __forceinline__ float silu_f(float v) {
    float s = __builtin_amdgcn_rcpf(1.0f + __builtin_amdgcn_exp2f(-v * L2E));
    return v * s;
}

__device__ __forceinline__ float comp4(const float4& f, int k) {
    return k == 0 ? f.x : k == 1 ? f.y : k == 2 ? f.z : f.w;
}

__device__ __forceinline__ void set4(float4& f, int k, float v) {
    if (k == 0) f.x = v; else if (k == 1) f.y = v; else if (k == 2) f.z = v; else f.w = v;
}

// ws layout (SoA, coalesced):
//   wsq[(n*NC + c)*NCH + bd]   n in [0,16)
//   wsS[c*NCH + bd]            at offset 16*NC*NCH

// Pass 1: per (256-channel group, chunk) local scan from zero -> (q[16], S).
template<int NC>
__global__ __launch_bounds__(256, 3) void k_pass1(
        const float* __restrict__ u, const float* __restrict__ delta,
        const float* __restrict__ A, const float* __restrict__ Bm,
        float* __restrict__ ws) {
    constexpr int LC = SEQ / NC;
    constexpr int NT = LC / TT;
    __shared__ float Ub[256 * ST];
    __shared__ float Db[256 * ST];
    __shared__ float Bc[LC * 20];          // [t][16 + 4 pad]

    int tid = threadIdx.x;
    int g = blockIdx.x & (NGRP - 1);       // NGRP == 32
    int c = blockIdx.x >> 5;               // wave-uniform
    int chBase = g << 8;
    int b = chBase >> 11;
    int bd = chBase + tid;
    int d = bd & (DIN - 1);

    float A2[NSTATE];
    {
        const float* Ar = A + (size_t)d * NSTATE;
        #pragma unroll
        for (int n = 0; n < NSTATE; ++n) A2[n] = Ar[n] * L2E;
    }

    const float* ug = u + (size_t)chBase * SEQ + (size_t)c * LC;
    const float* dg = delta + (size_t)chBase * SEQ + (size_t)c * LC;
    const float* Bg = Bm + (size_t)b * NSTATE * SEQ + (size_t)c * LC;

    // Stage whole-chunk B, transposed to [t][n] (coalesced reads over t).
    #pragma unroll
    for (int i = 0; i < LC * NSTATE / 256; ++i) {
        int e = i * 256 + tid;
        int n = e / LC;
        int t = e % LC;
        Bc[t * 20 + n] = Bg[(size_t)n * SEQ + t];
    }

    float x[NSTATE];
    #pragma unroll
    for (int n = 0; n < NSTATE; ++n) x[n] = 0.0f;
    float S = 0.0f;

    // Register prefetch of tile 0 (lane-along-t: 16 full lines / wave-inst).
    float4 uvr[4], dvr[4];
    #pragma unroll
    for (int it = 0; it < 4; ++it) {
        int r = it * 64 + (tid >> 2), cq = (tid & 3) * 4;
        uvr[it] = *(const float4*)(ug + (size_t)r * SEQ + cq);
        dvr[it] = *(const float4*)(dg + (size_t)r * SEQ + cq);
    }

    for (int tile = 0; tile < NT; ++tile) {
        int tb = tile * TT;
        __syncthreads();                       // prev tile's LDS reads done
        #pragma unroll
        for (int it = 0; it < 4; ++it) {
            int r = it * 64 + (tid >> 2), cq = (tid & 3) * 4;
            *(float4*)(&Ub[r * ST + cq]) = uvr[it];
            *(float4*)(&Db[r * ST + cq]) = dvr[it];
        }
        __syncthreads();
        if (tile + 1 < NT) {                   // prefetch next tile under compute
            #pragma unroll
            for (int it = 0; it < 4; ++it) {
                int r = it * 64 + (tid >> 2), cq = (tid & 3) * 4;
                uvr[it] = *(const float4*)(ug + (size_t)r * SEQ + tb + TT + cq);
                dvr[it] = *(const float4*)(dg + (size_t)r * SEQ + tb + TT + cq);
            }
        }
        #pragma unroll
        for (int t4 = 0; t4 < TT / 4; ++t4) {
            float4 u4 = *(const float4*)(&Ub[tid * ST + t4 * 4]);
            float4 d4 = *(const float4*)(&Db[tid * ST + t4 * 4]);
            #pragma unroll
            for (int k = 0; k < 4; ++k) {
                float dt = softplus_f(comp4(d4, k));
                S += dt;
                float du = dt * comp4(u4, k);
                int t = tb + t4 * 4 + k;
                const float4* Br = (const float4*)(&Bc[t * 20]);
                float bb[NSTATE];
                *(float4*)&bb[0] = Br[0]; *(float4*)&bb[4] = Br[1];
                *(float4*)&bb[8] = Br[2]; *(float4*)&bb[12] = Br[3];
                #pragma unroll
                for (int n = 0; n < NSTATE; ++n) {
                    float dA = __builtin_amdgcn_exp2f(A2[n] * dt);
                    x[n] = x[n] * dA + du * bb[n];
                }
            }
        }
    }

    float* wsq = ws;
    float* wsS = ws + (size_t)NSTATE * NC * NCH;
    #pragma unroll
    for (int n = 0; n < NSTATE; ++n) wsq[((size_t)n * NC + c) * NCH + bd] = x[n];
    wsS[(size_t)c * NCH + bd] = S;
}

// Pass 2: combine chunk operators. Parallel over (n, bd): 16x the threads of
// the old version (512 blocks, not 32). In-place overwrite q -> chunk prefix.
template<int NC>
__global__ __launch_bounds__(256) void k_pass2(
        const float* __restrict__ A, float* __restrict__ ws) {
    int idx = blockIdx.x * 256 + threadIdx.x;   // 0 .. 16*8192-1
    int n = idx >> 13;                          // NCH == 2^13
    int bd = idx & (NCH - 1);
    int d = bd & (DIN - 1);

    float A2 = A[(size_t)d * NSTATE + n] * L2E;
    float x = 0.0f;
    float* wsq = ws;
    float* wsS = ws + (size_t)NSTATE * NC * NCH;

    for (int c = 0; c < NC; ++c) {
        float S = wsS[(size_t)c * NCH + bd];
        float* p = wsq + ((size_t)n * NC + c) * NCH + bd;
        float q = *p;
        float P = __builtin_amdgcn_exp2f(A2 * S);
        *p = x;                                  // initial state for chunk c
        x = x * P + q;
    }
}

// Pass 3: rescan from chunk-initial state; emit gated y. Same LDS transpose;
// y reuses the u buffer (each thread overwrites exactly the b128 it just
// consumed), z is read and out written in the coalesced drain phase.
template<int NC>
__global__ __launch_bounds__(256, 3) void k_pass3(
        const float* __restrict__ u, const float* __restrict__ delta,
        const float* __restrict__ A, const float* __restrict__ Bm,
        const float* __restrict__ Cm, const float* __restrict__ Dv,
        const float* __restrict__ z, const float* __restrict__ ws,
        float* __restrict__ out) {
    constexpr int LC = SEQ / NC;
    constexpr int NT = LC / TT;
    __shared__ float Ub[256 * ST];          // u in compute, y for drain
    __shared__ float Db[256 * ST];
    __shared__ float Bc[LC * 20];
    __shared__ float Cc[LC * 20];

    int tid = threadIdx.x;
    int g = blockIdx.x & (NGRP - 1);
    int c = blockIdx.x >> 5;                // wave-uniform
    int chBase = g << 8;
    int b = chBase >> 11;
    int bd = chBase + tid;
    int d = bd & (DIN - 1);

    float A2[NSTATE];
    {
        const float* Ar = A + (size_t)d * NSTATE;
        #pragma unroll
        for (int n = 0; n < NSTATE; ++n) A2[n] = Ar[n] * L2E;
    }

    const float* ug = u + (size_t)chBase * SEQ + (size_t)c * LC;
    const float* dg = delta + (size_t)chBase * SEQ + (size_t)c * LC;
    const float* zg = z + (size_t)chBase * SEQ + (size_t)c * LC;
    float* og = out + (size_t)chBase * SEQ + (size_t)c * LC;
    const float* Bg = Bm + (size_t)b * NSTATE * SEQ + (size_t)c * LC;
    const float* Cg = Cm + (size_t)b * NSTATE * SEQ + (size_t)c * LC;

    #pragma unroll
    for (int i = 0; i < LC * NSTATE / 256; ++i) {
        int e = i * 256 + tid;
        int n = e / LC;
        int t = e % LC;
        Bc[t * 20 + n] = Bg[(size_t)n * SEQ + t];
        Cc[t * 20 + n] = Cg[(size_t)n * SEQ + t];
    }

    const float* wsq = ws;
    float x[NSTATE];
    #pragma unroll
    for (int n = 0; n < NSTATE; ++n)
        x[n] = wsq[((size_t)n * NC + c) * NCH + bd];
    float Dd = Dv[d];

    float4 uvr[4], dvr[4];
    #pragma unroll
    for (int it = 0; it < 4; ++it) {
        int r = it * 64 + (tid >> 2), cq = (tid & 3) * 4;
        uvr[it] = *(const float4*)(ug + (size_t)r * SEQ + cq);
        dvr[it] = *(const float4*)(dg + (size_t)r * SEQ + cq);
    }

    for (int tile = 0; tile < NT; ++tile) {
        int tb = tile * TT;
        __syncthreads();                       // prev drain done: Ub reusable
        #pragma unroll
        for (int it = 0; it < 4; ++it) {
            int r = it * 64 + (tid >> 2), cq = (tid & 3) * 4;
            *(float4*)(&Ub[r * ST + cq]) = uvr[it];
            *(float4*)(&Db[r * ST + cq]) = dvr[it];
        }
        __syncthreads();
        if (tile + 1 < NT) {
            #pragma unroll
            for (int it = 0; it < 4; ++it) {
                int r = it * 64 + (tid >> 2), cq = (tid & 3) * 4;
                uvr[it] = *(const float4*)(ug + (size_t)r * SEQ + tb + TT + cq);
                dvr[it] = *(const float4*)(dg + (size_t)r * SEQ + tb + TT + cq);
            }
        }
        #pragma unroll
        for (int t4 = 0; t4 < TT / 4; ++t4) {
            float4 u4 = *(const float4*)(&Ub[tid * ST + t4 * 4]);
            float4 d4 = *(const float4*)(&Db[tid * ST + t4 * 4]);
            float4 y4;
            #pragma unroll
            for (int k = 0; k < 4; ++k) {
                float uv = comp4(u4, k);
                float dt = softplus_f(comp4(d4, k));
                float du = dt * uv;
                int t = tb + t4 * 4 + k;
                const float4* Br = (const float4*)(&Bc[t * 20]);
                const float4* Cr = (const float4*)(&Cc[t * 20]);
                float bb[NSTATE], cc[NSTATE];
                *(float4*)&bb[0] = Br[0]; *(float4*)&bb[4] = Br[1];
                *(float4*)&bb[8] = Br[2]; *(float4*)&bb[12] = Br[3];
                *(float4*)&cc[0] = Cr[0]; *(float4*)&cc[4] = Cr[1];
                *(float4*)&cc[8] = Cr[2]; *(float4*)&cc[12] = Cr[3];
                float acc = 0.0f;
                #pragma unroll
                for (int n = 0; n < NSTATE; ++n) {
                    float dA = __builtin_amdgcn_exp2f(A2[n] * dt);
                    x[n] = x[n] * dA + du * bb[n];
                    acc += x[n] * cc[n];
                }
                set4(y4, k, acc + Dd * uv);
            }
            // overwrite the exact u-b128 this thread just consumed
            *(float4*)(&Ub[tid * ST + t4 * 4]) = y4;
        }
        __syncthreads();                       // y complete in Ub
        #pragma unroll
        for (int it = 0; it < 4; ++it) {       // coalesced drain: gate + store
            int r = it * 64 + (tid >> 2), cq = (tid & 3) * 4;
            float4 y4 = *(const float4*)(&Ub[r * ST + cq]);
            float4 z4 = *(const float4*)(zg + (size_t)r * SEQ + tb + cq);
            float4 oo;
            #pragma unroll
            for (int k = 0; k < 4; ++k)
                set4(oo, k, comp4(y4, k) * silu_f(comp4(z4, k)));
            *(float4*)(og + (size_t)r * SEQ + tb + cq) = oo;
        }
    }
}

// Fallback if ws is too small: one thread per (b,d), full sequential scan.
__global__ __launch_bounds__(256) void k_simple(
        const float* __restrict__ u, const float* __restrict__ delta,
        const float* __restrict__ A, const float* __restrict__ Bm,
        const float* __restrict__ Cm, const float* __restrict__ Dv,
        const float* __restrict__ z, float* __restrict__ out) {
    int bd = blockIdx.x * 256 + threadIdx.x;
    int b  = bd >> 11;
    int d  = bd & (DIN - 1);

    float A2[NSTATE];
    const float* Ar = A + d * NSTATE;
    #pragma unroll
    for (int n = 0; n < NSTATE; ++n) A2[n] = Ar[n] * L2E;
    float x[NSTATE];
    #pragma unroll
    for (int n = 0; n < NSTATE; ++n) x[n] = 0.0f;

    float Dd = Dv[d];
    size_t base = (size_t)bd * SEQ;
    const float4* u4 = (const float4*)(u + base);
    const float4* d4 = (const float4*)(delta + base);
    const float4* z4 = (const float4*)(z + base);
    float4* o4 = (float4*)(out + base);
    const float* Bp = Bm + (size_t)b * NSTATE * SEQ;
    const float* Cp = Cm + (size_t)b * NSTATE * SEQ;

    for (int t4 = 0; t4 < SEQ / 4; ++t4) {
        float4 uu = u4[t4];
        float4 dd = d4[t4];
        float4 zz = z4[t4];
        float4 yy;
        #pragma unroll
        for (int k = 0; k < 4; ++k) {
            float uv = comp4(uu, k);
            float dt = softplus_f(comp4(dd, k));
            float du = dt * uv;
            int t = t4 * 4 + k;
            float acc = 0.0f;
            #pragma unroll
            for (int n = 0; n < NSTATE; ++n) {
                float dA = __builtin_amdgcn_exp2f(A2[n] * dt);
                x[n] = x[n] * dA + du * Bp[n * SEQ + t];
                acc += x[n] * Cp[n * SEQ + t];
            }
            float y = acc + Dd * uv;
            y = y * silu_f(comp4(zz, k));
            set4(yy, k, y);
        }
        o4[t4] = yy;
    }
}

template<int NC>
static void launch_chunked(const float* u, const float* delta, const float* A,
                           const float* Bm, const float* Cm, const float* Dv,
                           const float* z, float* ws, float* out, hipStream_t stream) {
    k_pass1<NC><<<NGRP * NC, 256, 0, stream>>>(u, delta, A, Bm, ws);
    k_pass2<NC><<<(NSTATE * NCH) / 256, 256, 0, stream>>>(A, ws);
    k_pass3<NC><<<NGRP * NC, 256, 0, stream>>>(u, delta, A, Bm, Cm, Dv, z, ws, out);
}

extern "C" void kernel_launch(void* const* d_in, const int* in_sizes, int n_in,
                              void* d_out, int out_size, void* d_ws, size_t ws_size,
                              hipStream_t stream) {
    const float* u     = (const float*)d_in[0];
    const float* delta = (const float*)d_in[1];
    const float* A     = (const float*)d_in[2];
    const float* Bm    = (const float*)d_in[3];
    const float* Cm    = (const float*)d_in[4];
    const float* Dv    = (const float*)d_in[5];
    const float* z     = (const float*)d_in[6];
    float* out = (float*)d_out;
    float* ws = (float*)d_ws;

    size_t need64 = (size_t)(NSTATE + 1) * 64 * NCH * sizeof(float);
    size_t need32 = (size_t)(NSTATE + 1) * 32 * NCH * sizeof(float);
    size_t need16 = (size_t)(NSTATE + 1) * 16 * NCH * sizeof(float);
    if (ws_size >= need64) {
        launch_chunked<64>(u, delta, A, Bm, Cm, Dv, z, ws, out, stream);
    } else if (ws_size >= need32) {
        launch_chunked<32>(u, delta, A, Bm, Cm, Dv, z, ws, out, stream);
    } else if (ws_size >= need16) {
        launch_chunked<16>(u, delta, A, Bm, Cm, Dv, z, ws, out, stream);
    } else {
        k_simple<<<NCH / 256, 256, 0, stream>>>(u, delta, A, Bm, Cm, Dv, z, out);
    }
}

// Round 2
// 377.924 us; speedup vs baseline: 1.2170x; 1.1775x over previous
//
#include <hip/hip_runtime.h>

// Mamba selective scan, fp32. u,delta,z:(4,2048,2048) A:(2048,16)
// B,C:(4,16,2048) D:(2048,). Output y:(4,2048,2048).
// 3-pass chunked scan (chunk op = (S=sum dt, q=local scan)).
// R5: 128-byte line discipline. R4's TT=16 split every 128B L2 line into
// two 64B halves touched in consecutive tiles (~5us apart) -> line evicted
// in between -> ~2x refetch + write amplification (F=325MB vs 225 ideal,
// W=252 vs 67). Now TT=32: every global access is a full 128B line-row
// (8 lanes x dwordx4), touched exactly once. LDS stride 36 floats ->
// conflict-free b128 in stage/compute/drain ((9r+q)&7 bijective). z is
// prefetched into registers (needs no transpose), so the drain phase never
// waits on memory. 2 blocks/CU; each block front-loads a ~64KB burst.

#define BATCHSZ 4
#define DIN 2048
#define NSTATE 16
#define SEQ 2048
#define NCH (BATCHSZ * DIN)     // 8192 channels
#define NGRP (NCH / 256)        // 32 channel-groups of 256
#define TT 32                   // time tile: 128 B per row = one L2 line
#define ST 36                   // LDS row stride (floats): b128 slot (9r+q)&7 bijective
#define L2E 1.44269504f

__device__ __forceinline__ float softplus_f(float v) {
    float e = __builtin_amdgcn_exp2f(v * L2E);
    return 0.69314718f * __builtin_amdgcn_logf(1.0f + e);
}

__device__ __forceinline__ float silu_f(float v) {
    float s = __builtin_amdgcn_rcpf(1.0f + __builtin_amdgcn_exp2f(-v * L2E));
    return v * s;
}

__device__ __forceinline__ float comp4(const float4& f, int k) {
    return k == 0 ? f.x : k == 1 ? f.y : k == 2 ? f.z : f.w;
}

__device__ __forceinline__ void set4(float4& f, int k, float v) {
    if (k == 0) f.x = v; else if (k == 1) f.y = v; else if (k == 2) f.z = v; else f.w = v;
}

// ws layout (SoA, coalesced):
//   wsq[(n*NC + c)*NCH + bd]   n in [0,16)
//   wsS[c*NCH + bd]            at offset 16*NC*NCH

// Pass 1: per (256-channel group, chunk) local scan from zero -> (q[16], S).
template<int NC>
__global__ __launch_bounds__(256, 2) void k_pass1(
        const float* __restrict__ u, const float* __restrict__ delta,
        const float* __restrict__ A, const float* __restrict__ Bm,
        float* __restrict__ ws) {
    constexpr int LC = SEQ / NC;
    constexpr int NT = LC / TT;
    __shared__ float Ub[256 * ST];
    __shared__ float Db[256 * ST];
    __shared__ float Bc[LC * 20];          // [t][16 + 4 pad]

    int tid = threadIdx.x;
    int g = blockIdx.x & (NGRP - 1);       // NGRP == 32
    int c = blockIdx.x >> 5;               // wave-uniform
    int chBase = g << 8;
    int b = chBase >> 11;
    int bd = chBase + tid;
    int d = bd & (DIN - 1);

    float A2[NSTATE];
    {
        const float* Ar = A + (size_t)d * NSTATE;
        #pragma unroll
        for (int n = 0; n < NSTATE; ++n) A2[n] = Ar[n] * L2E;
    }

    const float* ug = u + (size_t)chBase * SEQ + (size_t)c * LC;
    const float* dg = delta + (size_t)chBase * SEQ + (size_t)c * LC;
    const float* Bg = Bm + (size_t)b * NSTATE * SEQ + (size_t)c * LC;

    // Stage whole-chunk B, transposed to [t][n].
    #pragma unroll
    for (int i = 0; i < LC * NSTATE / 256; ++i) {
        int e = i * 256 + tid;
        int n = e / LC;
        int t = e % LC;
        Bc[t * 20 + n] = Bg[(size_t)n * SEQ + t];
    }

    float x[NSTATE];
    #pragma unroll
    for (int n = 0; n < NSTATE; ++n) x[n] = 0.0f;
    float S = 0.0f;

    for (int tile = 0; tile < NT; ++tile) {
        int tb = tile * TT;
        __syncthreads();                   // prev tile's LDS reads done
        #pragma unroll
        for (int it = 0; it < 8; ++it) {   // 8 rows/wave-inst, full 128B lines
            int r = it * 32 + (tid >> 3), cq = (tid & 7) * 4;
            *(float4*)(&Ub[r * ST + cq]) = *(const float4*)(ug + (size_t)r * SEQ + tb + cq);
            *(float4*)(&Db[r * ST + cq]) = *(const float4*)(dg + (size_t)r * SEQ + tb + cq);
        }
        __syncthreads();
        #pragma unroll
        for (int t4 = 0; t4 < TT / 4; ++t4) {
            float4 u4 = *(const float4*)(&Ub[tid * ST + t4 * 4]);
            float4 d4 = *(const float4*)(&Db[tid * ST + t4 * 4]);
            #pragma unroll
            for (int k = 0; k < 4; ++k) {
                float dt = softplus_f(comp4(d4, k));
                S += dt;
                float du = dt * comp4(u4, k);
                int t = tb + t4 * 4 + k;
                const float4* Br = (const float4*)(&Bc[t * 20]);
                float bb[NSTATE];
                *(float4*)&bb[0] = Br[0]; *(float4*)&bb[4] = Br[1];
                *(float4*)&bb[8] = Br[2]; *(float4*)&bb[12] = Br[3];
                #pragma unroll
                for (int n = 0; n < NSTATE; ++n) {
                    float dA = __builtin_amdgcn_exp2f(A2[n] * dt);
                    x[n] = x[n] * dA + du * bb[n];
                }
            }
        }
    }

    float* wsq = ws;
    float* wsS = ws + (size_t)NSTATE * NC * NCH;
    #pragma unroll
    for (int n = 0; n < NSTATE; ++n) wsq[((size_t)n * NC + c) * NCH + bd] = x[n];
    wsS[(size_t)c * NCH + bd] = S;
}

// Pass 2: combine chunk operators, parallel over (n, bd). In-place q -> prefix.
template<int NC>
__global__ __launch_bounds__(256) void k_pass2(
        const float* __restrict__ A, float* __restrict__ ws) {
    int idx = blockIdx.x * 256 + threadIdx.x;   // 0 .. 16*8192-1
    int n = idx >> 13;                          // NCH == 2^13
    int bd = idx & (NCH - 1);
    int d = bd & (DIN - 1);

    float A2 = A[(size_t)d * NSTATE + n] * L2E;
    float x = 0.0f;
    float* wsq = ws;
    float* wsS = ws + (size_t)NSTATE * NC * NCH;

    for (int c = 0; c < NC; ++c) {
        float S = wsS[(size_t)c * NCH + bd];
        float* p = wsq + ((size_t)n * NC + c) * NCH + bd;
        float q = *p;
        float P = __builtin_amdgcn_exp2f(A2 * S);
        *p = x;                                  // initial state for chunk c
        x = x * P + q;
    }
}

// Pass 3: rescan from chunk-initial state; emit gated y. y transposes back
// through Ub (each thread overwrites the exact b128 it consumed); z goes
// straight to registers during the stage phase (no transpose needed).
template<int NC>
__global__ __launch_bounds__(256, 2) void k_pass3(
        const float* __restrict__ u, const float* __restrict__ delta,
        const float* __restrict__ A, const float* __restrict__ Bm,
        const float* __restrict__ Cm, const float* __restrict__ Dv,
        const float* __restrict__ z, const float* __restrict__ ws,
        float* __restrict__ out) {
    constexpr int LC = SEQ / NC;
    constexpr int NT = LC / TT;
    __shared__ float Ub[256 * ST];          // u in compute, y for drain
    __shared__ float Db[256 * ST];
    __shared__ float Bc[LC * 20];
    __shared__ float Cc[LC * 20];

    int tid = threadIdx.x;
    int g = blockIdx.x & (NGRP - 1);
    int c = blockIdx.x >> 5;                // wave-uniform
    int chBase = g << 8;
    int b = chBase >> 11;
    int bd = chBase + tid;
    int d = bd & (DIN - 1);

    float A2[NSTATE];
    {
        const float* Ar = A + (size_t)d * NSTATE;
        #pragma unroll
        for (int n = 0; n < NSTATE; ++n) A2[n] = Ar[n] * L2E;
    }

    const float* ug = u + (size_t)chBase * SEQ + (size_t)c * LC;
    const float* dg = delta + (size_t)chBase * SEQ + (size_t)c * LC;
    const float* zg = z + (size_t)chBase * SEQ + (size_t)c * LC;
    float* og = out + (size_t)chBase * SEQ + (size_t)c * LC;
    const float* Bg = Bm + (size_t)b * NSTATE * SEQ + (size_t)c * LC;
    const float* Cg = Cm + (size_t)b * NSTATE * SEQ + (size_t)c * LC;

    #pragma unroll
    for (int i = 0; i < LC * NSTATE / 256; ++i) {
        int e = i * 256 + tid;
        int n = e / LC;
        int t = e % LC;
        Bc[t * 20 + n] = Bg[(size_t)n * SEQ + t];
        Cc[t * 20 + n] = Cg[(size_t)n * SEQ + t];
    }

    const float* wsq = ws;
    float x[NSTATE];
    #pragma unroll
    for (int n = 0; n < NSTATE; ++n)
        x[n] = wsq[((size_t)n * NC + c) * NCH + bd];
    float Dd = Dv[d];

    for (int tile = 0; tile < NT; ++tile) {
        int tb = tile * TT;
        __syncthreads();                   // prev drain's Ub reads done
        float4 zr[8];
        #pragma unroll
        for (int it = 0; it < 8; ++it) {   // full 128B lines, touched once
            int r = it * 32 + (tid >> 3), cq = (tid & 7) * 4;
            *(float4*)(&Ub[r * ST + cq]) = *(const float4*)(ug + (size_t)r * SEQ + tb + cq);
            *(float4*)(&Db[r * ST + cq]) = *(const float4*)(dg + (size_t)r * SEQ + tb + cq);
            zr[it] = *(const float4*)(zg + (size_t)r * SEQ + tb + cq);
        }
        __syncthreads();
        #pragma unroll
        for (int t4 = 0; t4 < TT / 4; ++t4) {
            float4 u4 = *(const float4*)(&Ub[tid * ST + t4 * 4]);
            float4 d4 = *(const float4*)(&Db[tid * ST + t4 * 4]);
            float4 y4;
            #pragma unroll
            for (int k = 0; k < 4; ++k) {
                float uv = comp4(u4, k);
                float dt = softplus_f(comp4(d4, k));
                float du = dt * uv;
                int t = tb + t4 * 4 + k;
                const float4* Br = (const float4*)(&Bc[t * 20]);
                const float4* Cr = (const float4*)(&Cc[t * 20]);
                float bb[NSTATE], cc[NSTATE];
                *(float4*)&bb[0] = Br[0]; *(float4*)&bb[4] = Br[1];
                *(float4*)&bb[8] = Br[2]; *(float4*)&bb[12] = Br[3];
                *(float4*)&cc[0] = Cr[0]; *(float4*)&cc[4] = Cr[1];
                *(float4*)&cc[8] = Cr[2]; *(float4*)&cc[12] = Cr[3];
                float acc = 0.0f;
                #pragma unroll
                for (int n = 0; n < NSTATE; ++n) {
                    float dA = __builtin_amdgcn_exp2f(A2[n] * dt);
                    x[n] = x[n] * dA + du * bb[n];
                    acc += x[n] * cc[n];
                }
                set4(y4, k, acc + Dd * uv);
            }
            // overwrite the exact u-b128 this thread just consumed
            *(float4*)(&Ub[tid * ST + t4 * 4]) = y4;
        }
        __syncthreads();                   // y complete in Ub
        #pragma unroll
        for (int it = 0; it < 8; ++it) {   // coalesced drain: gate + store
            int r = it * 32 + (tid >> 3), cq = (tid & 7) * 4;
            float4 y4 = *(const float4*)(&Ub[r * ST + cq]);
            float4 oo;
            #pragma unroll
            for (int k = 0; k < 4; ++k)
                set4(oo, k, comp4(y4, k) * silu_f(comp4(zr[it], k)));
            *(float4*)(og + (size_t)r * SEQ + tb + cq) = oo;
        }
    }
}

// Fallback if ws is too small: one thread per (b,d), full sequential scan.
__global__ __launch_bounds__(256) void k_simple(
        const float* __restrict__ u, const float* __restrict__ delta,
        const float* __restrict__ A, const float* __restrict__ Bm,
        const float* __restrict__ Cm, const float* __restrict__ Dv,
        const float* __restrict__ z, float* __restrict__ out) {
    int bd = blockIdx.x * 256 + threadIdx.x;
    int b  = bd >> 11;
    int d  = bd & (DIN - 1);

    float A2[NSTATE];
    const float* Ar = A + d * NSTATE;
    #pragma unroll
    for (int n = 0; n < NSTATE; ++n) A2[n] = Ar[n] * L2E;
    float x[NSTATE];
    #pragma unroll
    for (int n = 0; n < NSTATE; ++n) x[n] = 0.0f;

    float Dd = Dv[d];
    size_t base = (size_t)bd * SEQ;
    const float4* u4 = (const float4*)(u + base);
    const float4* d4 = (const float4*)(delta + base);
    const float4* z4 = (const float4*)(z + base);
    float4* o4 = (float4*)(out + base);
    const float* Bp = Bm + (size_t)b * NSTATE * SEQ;
    const float* Cp = Cm + (size_t)b * NSTATE * SEQ;

    for (int t4 = 0; t4 < SEQ / 4; ++t4) {
        float4 uu = u4[t4];
        float4 dd = d4[t4];
        float4 zz = z4[t4];
        float4 yy;
        #pragma unroll
        for (int k = 0; k < 4; ++k) {
            float uv = comp4(uu, k);
            float dt = softplus_f(comp4(dd, k));
            float du = dt * uv;
            int t = t4 * 4 + k;
            float acc = 0.0f;
            #pragma unroll
            for (int n = 0; n < NSTATE; ++n) {
                float dA = __builtin_amdgcn_exp2f(A2[n] * dt);
                x[n] = x[n] * dA + du * Bp[n * SEQ + t];
                acc += x[n] * Cp[n * SEQ + t];
            }
            float y = acc + Dd * uv;
            y = y * silu_f(comp4(zz, k));
            set4(yy, k, y);
        }
        o4[t4] = yy;
    }
}

template<int NC>
static void launch_chunked(const float* u, const float* delta, const float* A,
                           const float* Bm, const float* Cm, const float* Dv,
                           const float* z, float* ws, float* out, hipStream_t stream) {
    k_pass1<NC><<<NGRP * NC, 256, 0, stream>>>(u, delta, A, Bm, ws);
    k_pass2<NC><<<(NSTATE * NCH) / 256, 256, 0, stream>>>(A, ws);
    k_pass3<NC><<<NGRP * NC, 256, 0, stream>>>(u, delta, A, Bm, Cm, Dv, z, ws, out);
}

extern "C" void kernel_launch(void* const* d_in, const int* in_sizes, int n_in,
                              void* d_out, int out_size, void* d_ws, size_t ws_size,
                              hipStream_t stream) {
    const float* u     = (const float*)d_in[0];
    const float* delta = (const float*)d_in[1];
    const float* A     = (const float*)d_in[2];
    const float* Bm    = (const float*)d_in[3];
    const float* Cm    = (const float*)d_in[4];
    const float* Dv    = (const float*)d_in[5];
    const float* z     = (const float*)d_in[6];
    float* out = (float*)d_out;
    float* ws = (float*)d_ws;

    size_t need64 = (size_t)(NSTATE + 1) * 64 * NCH * sizeof(float);
    size_t need32 = (size_t)(NSTATE + 1) * 32 * NCH * sizeof(float);
    size_t need16 = (size_t)(NSTATE + 1) * 16 * NCH * sizeof(float);
    if (ws_size >= need64) {
        launch_chunked<64>(u, delta, A, Bm, Cm, Dv, z, ws, out, stream);
    } else if (ws_size >= need32) {
        launch_chunked<32>(u, delta, A, Bm, Cm, Dv, z, ws, out, stream);
    } else if (ws_size >= need16) {
        launch_chunked<16>(u, delta, A, Bm, Cm, Dv, z, ws, out, stream);
    } else {
        k_simple<<<NCH / 256, 256, 0, stream>>>(u, delta, A, Bm, Cm, Dv, z, out);
    }
}